// Round 3
// baseline (87.472 us; speedup 1.0000x reference)
//
#include <hip/hip_runtime.h>
#include <hip/hip_bf16.h>

#define NN 4096
#define SJ 16
#define JCH (NN / SJ)   // 256
#define JITERS (JCH / 32)  // 8
#define LOG2E 1.44269504f

typedef __attribute__((ext_vector_type(4))) float f32x4;
typedef __attribute__((ext_vector_type(4))) int i32x4;
typedef __attribute__((ext_vector_type(4))) unsigned int u32x4;
typedef __attribute__((ext_vector_type(8))) short short8;

// packed bf16 conversion: 2 f32 -> 1 dword (native v_cvt_pk_bf16_f32)
__device__ __forceinline__ unsigned pk2(float a, float b) {
    float2 t; t.x = a; t.y = b;
    __hip_bfloat162 h = __float22bfloat162_rn(t);
    unsigned r;
    __builtin_memcpy(&r, &h, 4);
    return r;
}

__device__ __forceinline__ short8 load8_bf(const float* __restrict__ p) {
    f32x4 a = *(const f32x4*)p;
    f32x4 b = *(const f32x4*)(p + 4);
    u32x4 v = {pk2(a[0], a[1]), pk2(a[2], a[3]), pk2(b[0], b[1]), pk2(b[2], b[3])};
    return __builtin_bit_cast(short8, v);
}

// Kernel 1: h = x @ W^T (bf16 MFMA), fused epilogue:
//   esT[h][i] = log2e * sum_d h[i,h,d]*attn_src[h,d]
//   edT[h][j] = log2e * sum_d h[j,h,d]*attn_dst[h,d]
//   hT[h][d][j] = bf16(h[j,h,d])   (transposed for B-fragment loads)
__global__ __launch_bounds__(256) void k1_proj(
        const float* __restrict__ x, const float* __restrict__ W,
        const float* __restrict__ asrc, const float* __restrict__ adst,
        unsigned short* __restrict__ hT, float* __restrict__ esT,
        float* __restrict__ edT) {
    const int ibase = blockIdx.x * 16;
    const int w = threadIdx.x >> 6;
    const int lane = threadIdx.x & 63;
    const int grp = lane >> 4, li = lane & 15;

    const float* xrow = x + (ibase + li) * 128;
    const float* w0 = W + (w * 32 + li) * 128;
    const float* w1 = W + (w * 32 + 16 + li) * 128;

    f32x4 c0 = {0.f, 0.f, 0.f, 0.f}, c1 = {0.f, 0.f, 0.f, 0.f};
#pragma unroll
    for (int ko = 0; ko < 128; ko += 32) {
        const int kk = ko + grp * 8;
        short8 a = load8_bf(xrow + kk);
        short8 b0 = load8_bf(w0 + kk);
        short8 b1 = load8_bf(w1 + kk);
        c0 = __builtin_amdgcn_mfma_f32_16x16x32_bf16(a, b0, c0, 0, 0, 0);
        c1 = __builtin_amdgcn_mfma_f32_16x16x32_bf16(a, b1, c1, 0, 0, 0);
    }
    // C layout: col = li (output col within tile), row = grp*4 + reg.
    const float as0 = asrc[w * 32 + li], as1 = asrc[w * 32 + 16 + li];
    const float ad0 = adst[w * 32 + li], ad1 = adst[w * 32 + 16 + li];
    float pes[4], ped[4];
#pragma unroll
    for (int r = 0; r < 4; ++r) {
        pes[r] = c0[r] * as0 + c1[r] * as1;
        ped[r] = c0[r] * ad0 + c1[r] * ad1;
    }
#pragma unroll
    for (int m = 1; m < 16; m <<= 1) {
#pragma unroll
        for (int r = 0; r < 4; ++r) {
            pes[r] += __shfl_xor(pes[r], m);
            ped[r] += __shfl_xor(ped[r], m);
        }
    }
    if (li == 0) {
#pragma unroll
        for (int r = 0; r < 4; ++r) {
            const int row = ibase + grp * 4 + r;
            esT[w * NN + row] = pes[r] * LOG2E;
            edT[w * NN + row] = ped[r] * LOG2E;
        }
    }
#pragma unroll
    for (int r = 0; r < 4; ++r) {
        const int row = ibase + grp * 4 + r;
        hT[(w * 32 + li) * NN + row] = (unsigned short)__builtin_bit_cast(unsigned short, __float2bfloat16(c0[r]));
        hT[(w * 32 + 16 + li) * NN + row] = (unsigned short)__builtin_bit_cast(unsigned short, __float2bfloat16(c1[r]));
    }
}

struct LoadRegs {
    f32x4 e0, e1;
    i32x4 q00, q01, q10, q11;
    short8 b0, b1;
};

__device__ __forceinline__ LoadRegs do_loads(const float* __restrict__ edp,
                                             const int* __restrict__ a0p,
                                             const int* __restrict__ a1p,
                                             const unsigned short* __restrict__ h0,
                                             const unsigned short* __restrict__ h1,
                                             int j8) {
    LoadRegs r;
    r.e0 = *(const f32x4*)(edp + j8);
    r.e1 = *(const f32x4*)(edp + j8 + 4);
    r.q00 = *(const i32x4*)(a0p + j8);
    r.q01 = *(const i32x4*)(a0p + j8 + 4);
    r.q10 = *(const i32x4*)(a1p + j8);
    r.q11 = *(const i32x4*)(a1p + j8 + 4);
    r.b0 = *(const short8*)(h0 + j8);
    r.b1 = *(const short8*)(h1 + j8);
    return r;
}

__device__ __forceinline__ short8 buildA(float es, const f32x4 edlo, const f32x4 edhi,
                                         const i32x4 alo, const i32x4 ahi) {
    float p[8];
#pragma unroll
    for (int e = 0; e < 4; ++e) {
        float s = es + edlo[e];
        float v = __builtin_amdgcn_exp2f(fmaxf(s, 0.2f * s));
        p[e] = (alo[e] != 0) ? v : 0.0f;
    }
#pragma unroll
    for (int e = 0; e < 4; ++e) {
        float s = es + edhi[e];
        float v = __builtin_amdgcn_exp2f(fmaxf(s, 0.2f * s));
        p[4 + e] = (ahi[e] != 0) ? v : 0.0f;
    }
    u32x4 u = {pk2(p[0], p[1]), pk2(p[2], p[3]), pk2(p[4], p[5]), pk2(p[6], p[7])};
    return __builtin_bit_cast(short8, u);
}

// Kernel 3: main. Grid (128 i-tiles, SJ j-chunks) x 256 thr. Wave = head.
// i-tile = 32 rows (two 16-row MFMA subtiles). j-loop in blocks of 32 (K of MFMA),
// software-pipelined depth 1 (prefetch next iter's 8 loads before consuming current).
__global__ __launch_bounds__(256) void k3_main(
        const int* __restrict__ adj, const unsigned short* __restrict__ hT,
        const float* __restrict__ esT, const float* __restrict__ edT,
        float* __restrict__ numer, float* __restrict__ denom) {
    const int ibase = blockIdx.x * 32;
    const int jstart = blockIdx.y * JCH;
    const int head = threadIdx.x >> 6;
    const int lane = threadIdx.x & 63;
    const int grp = lane >> 4, li = lane & 15;

    const float es0 = esT[head * NN + ibase + li];
    const float es1 = esT[head * NN + ibase + 16 + li];
    const float* edp = edT + head * NN;
    const unsigned short* h0 = hT + (head * 32 + li) * NN;
    const unsigned short* h1 = hT + (head * 32 + 16 + li) * NN;
    const int* a0p = adj + (size_t)(ibase + li) * NN;
    const int* a1p = adj + (size_t)(ibase + 16 + li) * NN;

    f32x4 c00 = {0.f,0.f,0.f,0.f}, c01 = {0.f,0.f,0.f,0.f};
    f32x4 c10 = {0.f,0.f,0.f,0.f}, c11 = {0.f,0.f,0.f,0.f};
    f32x4 dn0 = {0.f,0.f,0.f,0.f}, dn1 = {0.f,0.f,0.f,0.f};
    short8 bones;
#pragma unroll
    for (int e = 0; e < 8; ++e) bones[e] = (short)0x3F80;  // bf16 1.0

    const int j8base = jstart + grp * 8;
    LoadRegs cur = do_loads(edp, a0p, a1p, h0, h1, j8base);
#pragma unroll
    for (int it = 0; it < JITERS; ++it) {
        LoadRegs nxt;
        if (it < JITERS - 1)
            nxt = do_loads(edp, a0p, a1p, h0, h1, j8base + (it + 1) * 32);

        const short8 A0 = buildA(es0, cur.e0, cur.e1, cur.q00, cur.q01);
        const short8 A1 = buildA(es1, cur.e0, cur.e1, cur.q10, cur.q11);

        c00 = __builtin_amdgcn_mfma_f32_16x16x32_bf16(A0, cur.b0, c00, 0, 0, 0);
        c01 = __builtin_amdgcn_mfma_f32_16x16x32_bf16(A0, cur.b1, c01, 0, 0, 0);
        c10 = __builtin_amdgcn_mfma_f32_16x16x32_bf16(A1, cur.b0, c10, 0, 0, 0);
        c11 = __builtin_amdgcn_mfma_f32_16x16x32_bf16(A1, cur.b1, c11, 0, 0, 0);
        dn0 = __builtin_amdgcn_mfma_f32_16x16x32_bf16(A0, bones, dn0, 0, 0, 0);
        dn1 = __builtin_amdgcn_mfma_f32_16x16x32_bf16(A1, bones, dn1, 0, 0, 0);

        if (it < JITERS - 1) cur = nxt;
    }

    // Epilogue: C layout col=li (d or rowsum-broadcast), row = grp*4+reg.
    const int r0 = ibase + grp * 4;
    float* nb = numer + head * 32 + li;
#pragma unroll
    for (int r = 0; r < 4; ++r) {
        atomicAdd(nb + (size_t)(r0 + r) * 128, c00[r]);
        atomicAdd(nb + (size_t)(r0 + r) * 128 + 16, c01[r]);
        atomicAdd(nb + (size_t)(r0 + 16 + r) * 128, c10[r]);
        atomicAdd(nb + (size_t)(r0 + 16 + r) * 128 + 16, c11[r]);
    }
    if (li == 0) {
#pragma unroll
        for (int r = 0; r < 4; ++r) {
            atomicAdd(denom + (r0 + r) * 4 + head, dn0[r]);
            atomicAdd(denom + (r0 + 16 + r) * 4 + head, dn1[r]);
        }
    }
}

// Kernel 4: out = numer / denom
__global__ __launch_bounds__(256) void k4_fin(const float* __restrict__ numer,
                                              const float* __restrict__ denom,
                                              float* __restrict__ out) {
    const int idx = blockIdx.x * 256 + threadIdx.x;
    const int node = idx >> 7;
    const int headc = (idx & 127) >> 5;
    out[idx] = numer[idx] / denom[node * 4 + headc];
}

extern "C" void kernel_launch(void* const* d_in, const int* in_sizes, int n_in,
                              void* d_out, int out_size, void* d_ws, size_t ws_size,
                              hipStream_t stream) {
    const float* x = (const float*)d_in[0];
    const int* adj = (const int*)d_in[1];
    const float* W = (const float*)d_in[2];
    const float* asrc = (const float*)d_in[3];
    const float* adst = (const float*)d_in[4];
    float* out = (float*)d_out;

    char* ws = (char*)d_ws;
    float* numer = (float*)ws;                                   // 4096*128*4 = 2 MB
    float* denom = (float*)(ws + (size_t)2097152);               // 4096*4*4 = 64 KB
    float* esT = (float*)(ws + (size_t)2097152 + 65536);         // 64 KB
    float* edT = (float*)(ws + (size_t)2097152 + 131072);        // 64 KB
    unsigned short* hT = (unsigned short*)(ws + (size_t)2097152 + 196608);  // 1 MB

    (void)hipMemsetAsync(numer, 0, 2097152 + 65536, stream);     // zero accumulators
    k1_proj<<<256, 256, 0, stream>>>(x, W, asrc, adst, hT, esT, edT);
    k3_main<<<dim3(128, SJ), 256, 0, stream>>>(adj, hT, esT, edT, numer, denom);
    k4_fin<<<2048, 256, 0, stream>>>(numer, denom, out);
}

// Round 4
// 59.360 us; speedup vs baseline: 1.4736x; 1.4736x over previous
//
#include <hip/hip_runtime.h>
#include <hip/hip_bf16.h>

#define NN 4096
#define SJ 8
#define JCH (NN / SJ)        // 512
#define JSTEP 64
#define NSTEPS (JCH / JSTEP) // 8
#define LOG2E 1.44269504f

typedef __attribute__((ext_vector_type(4))) float f32x4;
typedef __attribute__((ext_vector_type(4))) int i32x4;
typedef __attribute__((ext_vector_type(4))) unsigned int u32x4;
typedef __attribute__((ext_vector_type(8))) short short8;

// packed bf16 conversion: 2 f32 -> 1 dword (native v_cvt_pk_bf16_f32)
__device__ __forceinline__ unsigned pk2(float a, float b) {
    float2 t; t.x = a; t.y = b;
    __hip_bfloat162 h = __float22bfloat162_rn(t);
    unsigned r;
    __builtin_memcpy(&r, &h, 4);
    return r;
}

__device__ __forceinline__ short8 load8_bf(const float* __restrict__ p) {
    f32x4 a = *(const f32x4*)p;
    f32x4 b = *(const f32x4*)(p + 4);
    u32x4 v = {pk2(a[0], a[1]), pk2(a[2], a[3]), pk2(b[0], b[1]), pk2(b[2], b[3])};
    return __builtin_bit_cast(short8, v);
}

// Kernel 1: h = x @ W^T (bf16 MFMA), fused epilogue: es/ed scores (pre-scaled by
// log2e) and transposed bf16 hT[h*32+d][j].
__global__ __launch_bounds__(256) void k1_proj(
        const float* __restrict__ x, const float* __restrict__ W,
        const float* __restrict__ asrc, const float* __restrict__ adst,
        unsigned short* __restrict__ hT, float* __restrict__ esT,
        float* __restrict__ edT) {
    const int ibase = blockIdx.x * 16;
    const int w = threadIdx.x >> 6;
    const int lane = threadIdx.x & 63;
    const int grp = lane >> 4, li = lane & 15;

    const float* xrow = x + (ibase + li) * 128;
    const float* w0 = W + (w * 32 + li) * 128;
    const float* w1 = W + (w * 32 + 16 + li) * 128;

    f32x4 c0 = {0.f, 0.f, 0.f, 0.f}, c1 = {0.f, 0.f, 0.f, 0.f};
#pragma unroll
    for (int ko = 0; ko < 128; ko += 32) {
        const int kk = ko + grp * 8;
        short8 a = load8_bf(xrow + kk);
        short8 b0 = load8_bf(w0 + kk);
        short8 b1 = load8_bf(w1 + kk);
        c0 = __builtin_amdgcn_mfma_f32_16x16x32_bf16(a, b0, c0, 0, 0, 0);
        c1 = __builtin_amdgcn_mfma_f32_16x16x32_bf16(a, b1, c1, 0, 0, 0);
    }
    const float as0 = asrc[w * 32 + li], as1 = asrc[w * 32 + 16 + li];
    const float ad0 = adst[w * 32 + li], ad1 = adst[w * 32 + 16 + li];
    float pes[4], ped[4];
#pragma unroll
    for (int r = 0; r < 4; ++r) {
        pes[r] = c0[r] * as0 + c1[r] * as1;
        ped[r] = c0[r] * ad0 + c1[r] * ad1;
    }
#pragma unroll
    for (int m = 1; m < 16; m <<= 1) {
#pragma unroll
        for (int r = 0; r < 4; ++r) {
            pes[r] += __shfl_xor(pes[r], m);
            ped[r] += __shfl_xor(ped[r], m);
        }
    }
    if (li == 0) {
#pragma unroll
        for (int r = 0; r < 4; ++r) {
            const int row = ibase + grp * 4 + r;
            esT[w * NN + row] = pes[r] * LOG2E;
            edT[w * NN + row] = ped[r] * LOG2E;
        }
    }
#pragma unroll
    for (int r = 0; r < 4; ++r) {
        const int row = ibase + grp * 4 + r;
        hT[(w * 32 + li) * NN + row] = (unsigned short)__builtin_bit_cast(unsigned short, __float2bfloat16(c0[r]));
        hT[(w * 32 + 16 + li) * NN + row] = (unsigned short)__builtin_bit_cast(unsigned short, __float2bfloat16(c1[r]));
    }
}

__device__ __forceinline__ short8 buildA(float es, const f32x4 edlo, const f32x4 edhi,
                                         const i32x4 alo, const i32x4 ahi) {
    float p[8];
#pragma unroll
    for (int e = 0; e < 4; ++e) {
        float s = es + edlo[e];
        float v = __builtin_amdgcn_exp2f(fmaxf(s, 0.2f * s));
        p[e] = (alo[e] != 0) ? v : 0.0f;
    }
#pragma unroll
    for (int e = 0; e < 4; ++e) {
        float s = es + edhi[e];
        float v = __builtin_amdgcn_exp2f(fmaxf(s, 0.2f * s));
        p[4 + e] = (ahi[e] != 0) ? v : 0.0f;
    }
    u32x4 u = {pk2(p[0], p[1]), pk2(p[2], p[3]), pk2(p[4], p[5]), pk2(p[6], p[7])};
    return __builtin_bit_cast(short8, u);
}

// Kernel 3: main. Grid (128 i-tiles, SJ j-chunks) x 256 thr. Wave = head.
// adj tile [32 rows][64 j] staged to LDS via global_load_lds, double-buffered,
// 1 barrier/step. XOR chunk swizzle (c = p ^ (row&15)) applied on the GLOBAL
// source (LDS dest linear per rule 21) and inverted on the ds_read.
__global__ __launch_bounds__(256) void k3_main(
        const int* __restrict__ adj, const unsigned short* __restrict__ hT,
        const float* __restrict__ esT, const float* __restrict__ edT,
        float* __restrict__ numer, float* __restrict__ denom) {
    __shared__ unsigned int adjbuf[2][32 * 64];   // 2 x 8 KB

    const int ibase = blockIdx.x * 32;
    const int jstart = blockIdx.y * JCH;
    const int head = threadIdx.x >> 6;
    const int lane = threadIdx.x & 63;
    const int grp = lane >> 4, li = lane & 15;
    const int sub = lane >> 4, p = lane & 15;     // staging roles

    const float es0 = esT[head * NN + ibase + li];
    const float es1 = esT[head * NN + ibase + 16 + li];
    const float* edp = edT + head * NN;
    const unsigned short* h0 = hT + (head * 32 + li) * NN;
    const unsigned short* h1 = hT + (head * 32 + 16 + li) * NN;
    const unsigned int* adju = (const unsigned int*)adj;

    f32x4 c00 = {0.f,0.f,0.f,0.f}, c01 = {0.f,0.f,0.f,0.f};
    f32x4 c10 = {0.f,0.f,0.f,0.f}, c11 = {0.f,0.f,0.f,0.f};
    f32x4 dn0 = {0.f,0.f,0.f,0.f}, dn1 = {0.f,0.f,0.f,0.f};
    short8 bones;
#pragma unroll
    for (int e = 0; e < 8; ++e) bones[e] = (short)0x3F80;  // bf16 1.0

    // ---- staging lambda: wave `head` stages rows head*8 .. head*8+8 ----
    // row R, chunk-position p holds global chunk c = p ^ (R&15); LDS linear.
    auto stage = [&](unsigned int* dst, int jb) {
#pragma unroll
        for (int k = 0; k < 2; ++k) {
            const int R = head * 8 + k * 4 + sub;
            const int c = p ^ (R & 15);
            const unsigned int* g = adju + (size_t)(ibase + R) * NN + jb + c * 4;
            __builtin_amdgcn_global_load_lds(g, dst + (head * 8 + k * 4) * 64, 16, 0, 0);
        }
    };

    unsigned int* cur = &adjbuf[0][0];
    unsigned int* nxt = &adjbuf[1][0];

    stage(cur, jstart);
    __syncthreads();   // full vmcnt drain before first read

    for (int t = 0; t < NSTEPS; ++t) {
        const int jb = jstart + t * JSTEP;
        if (t + 1 < NSTEPS) stage(nxt, jb + JSTEP);

#pragma unroll
        for (int ks = 0; ks < 2; ++ks) {
            const int j0 = jb + ks * 32 + grp * 8;
            const f32x4 e0 = *(const f32x4*)(edp + j0);
            const f32x4 e1 = *(const f32x4*)(edp + j0 + 4);
            const short8 b0 = *(const short8*)(h0 + j0);
            const short8 b1 = *(const short8*)(h1 + j0);

            const int c0i = ks * 8 + grp * 2;
            // subtile 0: rows li; subtile 1: rows li+16 ((row&15)=li for both)
            const i32x4 q00 = *(const i32x4*)&cur[li * 64 + (c0i ^ li) * 4];
            const i32x4 q01 = *(const i32x4*)&cur[li * 64 + ((c0i + 1) ^ li) * 4];
            const i32x4 q10 = *(const i32x4*)&cur[(li + 16) * 64 + (c0i ^ li) * 4];
            const i32x4 q11 = *(const i32x4*)&cur[(li + 16) * 64 + ((c0i + 1) ^ li) * 4];

            const short8 A0 = buildA(es0, e0, e1, q00, q01);
            const short8 A1 = buildA(es1, e0, e1, q10, q11);

            c00 = __builtin_amdgcn_mfma_f32_16x16x32_bf16(A0, b0, c00, 0, 0, 0);
            c01 = __builtin_amdgcn_mfma_f32_16x16x32_bf16(A0, b1, c01, 0, 0, 0);
            c10 = __builtin_amdgcn_mfma_f32_16x16x32_bf16(A1, b0, c10, 0, 0, 0);
            c11 = __builtin_amdgcn_mfma_f32_16x16x32_bf16(A1, b1, c11, 0, 0, 0);
            dn0 = __builtin_amdgcn_mfma_f32_16x16x32_bf16(A0, bones, dn0, 0, 0, 0);
            dn1 = __builtin_amdgcn_mfma_f32_16x16x32_bf16(A1, bones, dn1, 0, 0, 0);
        }

        __syncthreads();   // drains stage vmcnt; nxt ready for next iteration
        unsigned int* tmp = cur; cur = nxt; nxt = tmp;
    }

    // Epilogue: C layout col=li, row = grp*4+reg.
    const int r0 = ibase + grp * 4;
    float* nb = numer + head * 32 + li;
#pragma unroll
    for (int r = 0; r < 4; ++r) {
        atomicAdd(nb + (size_t)(r0 + r) * 128, c00[r]);
        atomicAdd(nb + (size_t)(r0 + r) * 128 + 16, c01[r]);
        atomicAdd(nb + (size_t)(r0 + 16 + r) * 128, c10[r]);
        atomicAdd(nb + (size_t)(r0 + 16 + r) * 128 + 16, c11[r]);
    }
    if (li == 0) {
#pragma unroll
        for (int r = 0; r < 4; ++r) {
            atomicAdd(denom + (r0 + r) * 4 + head, dn0[r]);
            atomicAdd(denom + (r0 + 16 + r) * 4 + head, dn1[r]);
        }
    }
}

// Kernel 4: out = numer / denom
__global__ __launch_bounds__(256) void k4_fin(const float* __restrict__ numer,
                                              const float* __restrict__ denom,
                                              float* __restrict__ out) {
    const int idx = blockIdx.x * 256 + threadIdx.x;
    const int node = idx >> 7;
    const int headc = (idx & 127) >> 5;
    out[idx] = numer[idx] / denom[node * 4 + headc];
}

extern "C" void kernel_launch(void* const* d_in, const int* in_sizes, int n_in,
                              void* d_out, int out_size, void* d_ws, size_t ws_size,
                              hipStream_t stream) {
    const float* x = (const float*)d_in[0];
    const int* adj = (const int*)d_in[1];
    const float* W = (const float*)d_in[2];
    const float* asrc = (const float*)d_in[3];
    const float* adst = (const float*)d_in[4];
    float* out = (float*)d_out;

    char* ws = (char*)d_ws;
    float* numer = (float*)ws;                                   // 2 MB
    float* denom = (float*)(ws + (size_t)2097152);               // 64 KB
    float* esT = (float*)(ws + (size_t)2097152 + 65536);         // 64 KB
    float* edT = (float*)(ws + (size_t)2097152 + 131072);        // 64 KB
    unsigned short* hT = (unsigned short*)(ws + (size_t)2097152 + 196608);  // 1 MB

    (void)hipMemsetAsync(numer, 0, 2097152 + 65536, stream);     // zero accumulators
    k1_proj<<<256, 256, 0, stream>>>(x, W, asrc, adst, hT, esT, edT);
    k3_main<<<dim3(128, SJ), 256, 0, stream>>>(adj, hT, esT, edT, numer, denom);
    k4_fin<<<2048, 256, 0, stream>>>(numer, denom, out);
}